// Round 1
// baseline (1520.239 us; speedup 1.0000x reference)
//
#include <hip/hip_runtime.h>
#include <math.h>

#define N_NEU 256
#define D_DIM 32
#define KFD   16
#define KN    50
#define B_SZ  512
#define UINF  128
#define GAMMA 0.1f
#define DT    0.05f
#define NSTEP 20

// ---------------------------------------------------------------------------
// Kernel 1: normalized-feature similarity + top-KN selection per row.
// Grid 256 (one block per row n), block 256 (one thread per column j).
// Selection done by wave 0 with shuffle argmax (tie -> lowest index, matching
// jax.lax.top_k; only the selected SET + values matter for the weighted sum).
// Outputs transposed layouts idxT[k*256+n], valsT[k*256+n] for coalesced reads.
// ---------------------------------------------------------------------------
__global__ __launch_bounds__(256) void topk_kernel(const float* __restrict__ features,
                                                   int* __restrict__ idxT,
                                                   float* __restrict__ valsT) {
    __shared__ float fsh[N_NEU][KFD + 1];   // +1 pad: avoid 32-way bank conflicts
    __shared__ float sim_sh[N_NEU];
    const int n = blockIdx.x;
    const int j = threadIdx.x;

    float v[KFD];
    float s = 0.f;
#pragma unroll
    for (int d = 0; d < KFD; ++d) { v[d] = features[j * KFD + d]; s = fmaf(v[d], v[d], s); }
    const float nrm = sqrtf(s);
#pragma unroll
    for (int d = 0; d < KFD; ++d) fsh[j][d] = v[d] / nrm;   // match ref: divide by norm
    __syncthreads();

    float dot = 0.f;
#pragma unroll
    for (int d = 0; d < KFD; ++d) dot = fmaf(fsh[n][d], fsh[j][d], dot);
    sim_sh[j] = dot;
    __syncthreads();

    if (j < 64) {
        float l0 = sim_sh[j];
        float l1 = sim_sh[j + 64];
        float l2 = sim_sh[j + 128];
        float l3 = sim_sh[j + 192];
        for (int k = 0; k < KN; ++k) {
            // local argmax (ascending index order + strict '>' keeps lowest index on tie)
            float bv = l0; int bi = j;
            if (l1 > bv) { bv = l1; bi = j + 64; }
            if (l2 > bv) { bv = l2; bi = j + 128; }
            if (l3 > bv) { bv = l3; bi = j + 192; }
            // butterfly reduce across the wave, tie -> lowest index
            for (int off = 32; off > 0; off >>= 1) {
                float ov = __shfl_xor(bv, off, 64);
                int   oi = __shfl_xor(bi, off, 64);
                if (ov > bv || (ov == bv && oi < bi)) { bv = ov; bi = oi; }
            }
            if (j == 0) { valsT[k * N_NEU + n] = bv; idxT[k * N_NEU + n] = bi; }
            // invalidate the winner (static register indexing only)
            if ((bi & 63) == j) {
                const int q = bi >> 6;
                if      (q == 0) l0 = -INFINITY;
                else if (q == 1) l1 = -INFINITY;
                else if (q == 2) l2 = -INFINITY;
                else             l3 = -INFINITY;
            }
        }
    }
}

// ---------------------------------------------------------------------------
// Kernel 2: c[m,d] = sum_k u[m,k]*w_in[d,k] + b_in[d] + bias[n,d] + sig_b2[d]
// (all loop-invariant terms of the step update folded into one tensor).
// Block = 256 threads = 8 rows x 32 d. u tile staged in LDS (coalesced float4),
// w_in staged with +1 pad (stride 128 would be a 32-way conflict).
// ---------------------------------------------------------------------------
__global__ __launch_bounds__(256) void uproj_kernel(const float* __restrict__ u,
                                                    const float* __restrict__ w_in,
                                                    const float* __restrict__ b_in,
                                                    const float* __restrict__ bias,
                                                    const float* __restrict__ sig_b2,
                                                    float* __restrict__ c) {
    __shared__ float ush[8][UINF];
    __shared__ float wsh[D_DIM][UINF + 1];
    const int t = threadIdx.x;
    const long m0 = (long)blockIdx.x * 8;

    for (int i = t; i < D_DIM * UINF; i += 256) wsh[i >> 7][i & 127] = w_in[i];
    const float4 uv = reinterpret_cast<const float4*>(u)[m0 * 32 + t];
    *reinterpret_cast<float4*>(&ush[t >> 5][(t & 31) * 4]) = uv;
    __syncthreads();

    const int ml = t >> 5, d = t & 31;
    float acc = 0.f;
#pragma unroll 8
    for (int k = 0; k < UINF; ++k) acc = fmaf(ush[ml][k], wsh[d][k], acc);

    const long m = m0 + ml;
    const int  nn = (int)(m & (N_NEU - 1));
    c[m * D_DIM + d] = acc + b_in[d] + bias[nn * D_DIM + d] + sig_b2[d];
}

// ---------------------------------------------------------------------------
// Kernel 3: the 20-step recurrence. Grid 256 blocks x 512 threads;
// each block owns 2 batch items (bl = tid>>8), each thread one neuron.
// x[32], c[32] in registers; idx packed 4x8-bit into 13 registers;
// vals staged once in LDS (conflict-free reads: lane n -> vals_sh[k*256+n]);
// a exchanged via LDS each step (the only cross-thread dependency).
// a_bar from the reference is dead code (never feeds back into x) -> skipped.
// ---------------------------------------------------------------------------
__global__ __launch_bounds__(512, 2) void steps_kernel(const float* __restrict__ c,
                                                       const int* __restrict__ idxT,
                                                       const float* __restrict__ valsT,
                                                       const float* __restrict__ sig_w1,
                                                       const float* __restrict__ sig_b1,
                                                       const float* __restrict__ sig_w2,
                                                       float* __restrict__ out) {
    __shared__ float a_sh[2][N_NEU];
    __shared__ float vals_sh[KN * N_NEU];      // 50 KiB
    __shared__ float sw1[16], sb1[16];
    __shared__ float sw2t[16 * 32];            // [j][d]

    const int t  = threadIdx.x;
    const int bl = t >> 8;
    const int n  = t & (N_NEU - 1);
    const int b  = blockIdx.x * 2 + bl;

    for (int i = t; i < KN * N_NEU; i += 512) vals_sh[i] = valsT[i];
    if (t < 16) { sw1[t] = sig_w1[t]; sb1[t] = sig_b1[t]; }
    sw2t[(t & 15) * 32 + (t >> 4)] = sig_w2[t];   // transpose (D,16) -> [j][d]

    // pack the 50 neighbor indices (each < 256) into 13 u32 registers
    unsigned int idxp[13];
#pragma unroll
    for (int w = 0; w < 13; ++w) idxp[w] = 0u;
#pragma unroll
    for (int k = 0; k < KN; ++k) {
        const unsigned int ii = (unsigned int)idxT[k * N_NEU + n];
        idxp[k >> 2] |= ii << ((k & 3) * 8);
    }

    float x[D_DIM], cc[D_DIM];
    const float4* cp4 = reinterpret_cast<const float4*>(c + ((size_t)b * N_NEU + n) * D_DIM);
#pragma unroll
    for (int i = 0; i < 8; ++i) {
        const float4 cv = cp4[i];
        cc[4 * i + 0] = cv.x; cc[4 * i + 1] = cv.y;
        cc[4 * i + 2] = cv.z; cc[4 * i + 3] = cv.w;
    }
#pragma unroll
    for (int d = 0; d < D_DIM; ++d) x[d] = 0.f;
    __syncthreads();   // staging visible to all

    for (int s = 0; s < NSTEP; ++s) {
        // a = tanh(sqrt(sum x^2 + 1e-12))
        float nrm2 = 1e-12f;
#pragma unroll
        for (int d = 0; d < D_DIM; ++d) nrm2 = fmaf(x[d], x[d], nrm2);
        const float a = tanhf(sqrtf(nrm2));

        __syncthreads();            // previous step's gathers done
        a_sh[bl][n] = a;
        __syncthreads();            // a visible

        // sparse neighbor aggregation
        float syn = 0.f;
#pragma unroll
        for (int k = 0; k < KN; ++k) {
            const int ii = (int)((idxp[k >> 2] >> ((k & 3) * 8)) & 255u);
            syn = fmaf(a_sh[bl][ii], vals_sh[k * N_NEU + n], syn);
        }

        // x <- x + DT*(-GAMMA*x + cc)   (cc already holds u_proj+b_in+bias+sig_b2)
#pragma unroll
        for (int d = 0; d < D_DIM; ++d) x[d] = fmaf(DT, fmaf(-GAMMA, x[d], cc[d]), x[d]);

        // sigma MLP: 16 hidden, exact GELU, accumulate DT*g_j*w2[j][d] into x
#pragma unroll
        for (int j = 0; j < 16; ++j) {
            const float hj = fmaf(syn, sw1[j], sb1[j]);
            const float g  = 0.5f * hj * (1.0f + erff(hj * 0.70710678118654752f));
            const float gd = DT * g;
#pragma unroll
            for (int d = 0; d < D_DIM; ++d) x[d] = fmaf(gd, sw2t[j * 32 + d], x[d]);
        }
    }

    float4* op4 = reinterpret_cast<float4*>(out + ((size_t)b * N_NEU + n) * D_DIM);
#pragma unroll
    for (int i = 0; i < 8; ++i)
        op4[i] = make_float4(x[4 * i + 0], x[4 * i + 1], x[4 * i + 2], x[4 * i + 3]);
}

extern "C" void kernel_launch(void* const* d_in, const int* in_sizes, int n_in,
                              void* d_out, int out_size, void* d_ws, size_t ws_size,
                              hipStream_t stream) {
    const float* u        = (const float*)d_in[0];
    const float* features = (const float*)d_in[1];
    const float* bias     = (const float*)d_in[2];
    const float* w_in     = (const float*)d_in[3];
    const float* b_in     = (const float*)d_in[4];
    const float* sig_w1   = (const float*)d_in[5];
    const float* sig_b1   = (const float*)d_in[6];
    const float* sig_w2   = (const float*)d_in[7];
    const float* sig_b2   = (const float*)d_in[8];
    float* out = (float*)d_out;

    char*  ws    = (char*)d_ws;
    int*   idxT  = (int*)ws;                    // 50*256*4 = 51200 B
    float* valsT = (float*)(ws + 51200);        // 51200 B
    float* c     = (float*)(ws + 102400);       // 512*256*32*4 = 16 MiB

    hipLaunchKernelGGL(topk_kernel, dim3(N_NEU), dim3(256), 0, stream,
                       features, idxT, valsT);
    hipLaunchKernelGGL(uproj_kernel, dim3(B_SZ * N_NEU / 8), dim3(256), 0, stream,
                       u, w_in, b_in, bias, sig_b2, c);
    hipLaunchKernelGGL(steps_kernel, dim3(B_SZ / 2), dim3(512), 0, stream,
                       c, idxT, valsT, sig_w1, sig_b1, sig_w2, out);
}